// Round 5
// baseline (516.110 us; speedup 1.0000x reference)
//
#include <hip/hip_runtime.h>

#define Bsz   1024
#define Tlen  512
#define VOC   8
#define EDIM  32
#define HDIM  64
#define G4    256
#define SEQB  16                 // sequences per block (MFMA M=16)
#define NT    512                // 8 waves
#define NBLK  (Bsz / SEQB)       // 64 blocks

typedef _Float16 f16x8 __attribute__((ext_vector_type(8)));
typedef float    f32x4 __attribute__((ext_vector_type(4)));

__device__ __forceinline__ float ex2(float x) {
#if __has_builtin(__builtin_amdgcn_exp2f)
    return __builtin_amdgcn_exp2f(x);
#else
    return exp2f(x);
#endif
}
__device__ __forceinline__ float rcp_(float x) {
#if __has_builtin(__builtin_amdgcn_rcpf)
    return __builtin_amdgcn_rcpf(x);
#else
    return 1.0f / x;
#endif
}
__device__ __forceinline__ float sigm(float x) {
    return rcp_(1.0f + ex2(x * -1.4426950408889634f));
}
__device__ __forceinline__ float tanh_(float x) {
    return __builtin_fmaf(2.0f, rcp_(1.0f + ex2(x * -2.8853900817779268f)), -1.0f);
}

// ws: [0 .. 2048) packed layer0 gate table: float4{i,f,g,o}[voc][hcol]  (emb@Wih0^T + both biases)
//     [2048 .. 2304) bih1+bhh1
__global__ void precompute_kernel(const float* __restrict__ emb,
                                  const float* __restrict__ Wih0,
                                  const float* __restrict__ bih0,
                                  const float* __restrict__ bhh0,
                                  const float* __restrict__ bih1,
                                  const float* __restrict__ bhh1,
                                  float* __restrict__ ws) {
    int g = threadIdx.x;
    int v = blockIdx.x;
    if (v < VOC) {
        float acc = bih0[g] + bhh0[g];
        #pragma unroll
        for (int e = 0; e < EDIM; ++e)
            acc += Wih0[g * EDIM + e] * emb[v * EDIM + e];
        const int q = g >> 6, c = g & 63;      // gate type, hidden col
        ws[(v * 64 + c) * 4 + q] = acc;
    } else {
        ws[VOC * G4 + g] = bih1[g] + bhh1[g];
    }
}

// h LDS layout = A-fragment order for mfma_f32_16x16x32_f16 (same as validated R4):
__device__ __forceinline__ f16x8 read_h_frag(const _Float16* hb, int kc, int l) {
    int off = kc * 512 + ((l * 8) ^ ((l & 3) << 7));
    return *(const f16x8*)(hb + off);
}
__device__ __forceinline__ void write_h(_Float16* hb, int r, int c, float v) {
    int off = (c >> 5) * 512 +
              (((((c & 31) >> 3) * 128) + r * 8 + (c & 7)) ^ ((r & 3) << 7));
    hb[off] = (_Float16)v;
}

__device__ __forceinline__ void upd_elem(float a0, float a1, float a2, float a3,
                                         float& cs, float& hv) {
    float gi = sigm(a0), gf = sigm(a1), gg = tanh_(a2), go = sigm(a3);
    cs = gf * cs + gi * gg;
    hv = go * tanh_(cs);
}

__global__ __launch_bounds__(NT, 2)
void lstm_kernel(const int*   __restrict__ x,
                 const float* __restrict__ Whh0,
                 const float* __restrict__ Wih1,
                 const float* __restrict__ Whh1,
                 const float* __restrict__ Wfc,
                 const float* __restrict__ bfc,
                 const float* __restrict__ ws,
                 float* __restrict__ out) {
    __shared__ float4    stbl4[VOC * 64];        // 8 KB packed gate table
    __shared__ int       sxl[SEQB * Tlen];       // 32 KB tokens [seq][t]
    __shared__ _Float16  hbuf[2][2][1024];       // 8 KB  [buf][layer][frag elems]
    __shared__ float     sh1f[SEQB][HDIM + 1];   // final h1, fp32

    const int tid  = threadIdx.x;
    const int b0   = blockIdx.x * SEQB;
    const int l    = tid & 63;
    const int wid  = tid >> 6;
    const bool isL1 = (wid >= 4);
    const int w    = wid & 3;
    const int l15  = l & 15;
    const int kb   = (l >> 4) * 8;
    const int cq0  = 16 * w + l15;               // this lane's hidden col
    const int sxbase = (l >> 4) * 4 * Tlen;      // token row base (rows (l>>4)*4 + i)

    for (int i = tid; i < VOC * 64; i += NT)
        stbl4[i] = ((const float4*)ws)[i];
    for (int i = tid; i < SEQB * Tlen; i += NT)
        sxl[i] = x[b0 * Tlen + i];
    for (int i = tid; i < 2 * 2 * 1024; i += NT)
        ((_Float16*)hbuf)[i] = (_Float16)0.0f;

    // loop-invariant weight B-fragments (same as R4): lane holds W[col=64q+16w+l15][kc*32+kb+i]
    f16x8 wA0[4], wA1[4], wI0[4], wI1[4], wH0[4], wH1[4];
    float b1v[4];
    if (!isL1) {
        #pragma unroll
        for (int q = 0; q < 4; ++q) {
            const int cq = 64 * q + cq0;
            const float* p0 = Whh0 + cq * HDIM + kb;
            const float* p1 = Whh0 + cq * HDIM + 32 + kb;
            #pragma unroll
            for (int i = 0; i < 8; ++i) { wA0[q][i] = (_Float16)p0[i]; wA1[q][i] = (_Float16)p1[i]; }
        }
    } else {
        #pragma unroll
        for (int q = 0; q < 4; ++q) {
            const int cq = 64 * q + cq0;
            b1v[q] = ws[VOC * G4 + cq];
            const float* pi0 = Wih1 + cq * HDIM + kb;
            const float* pi1 = Wih1 + cq * HDIM + 32 + kb;
            const float* ph0 = Whh1 + cq * HDIM + kb;
            const float* ph1 = Whh1 + cq * HDIM + 32 + kb;
            #pragma unroll
            for (int i = 0; i < 8; ++i) {
                wI0[q][i] = (_Float16)pi0[i]; wI1[q][i] = (_Float16)pi1[i];
                wH0[q][i] = (_Float16)ph0[i]; wH1[q][i] = (_Float16)ph1[i];
            }
        }
    }

    float cst[4] = {0.0f, 0.0f, 0.0f, 0.0f};
    __syncthreads();

    // prefetch state (L0 waves): tq* = table quads for step k; tn* = tokens for step k+1
    f32x4 tq0, tq1, tq2, tq3;
    int   tn0, tn1, tn2, tn3;
    if (!isL1) {
        int tc0 = sxl[sxbase], tc1 = sxl[sxbase + Tlen], tc2 = sxl[sxbase + 2 * Tlen], tc3 = sxl[sxbase + 3 * Tlen];
        tq0 = *(const f32x4*)&stbl4[tc0 * 64 + cq0];
        tq1 = *(const f32x4*)&stbl4[tc1 * 64 + cq0];
        tq2 = *(const f32x4*)&stbl4[tc2 * 64 + cq0];
        tq3 = *(const f32x4*)&stbl4[tc3 * 64 + cq0];
        tn0 = sxl[sxbase + 1]; tn1 = sxl[sxbase + Tlen + 1];
        tn2 = sxl[sxbase + 2 * Tlen + 1]; tn3 = sxl[sxbase + 3 * Tlen + 1];
    }

    // iter k: layer0 step t=k, layer1 step t=k-1; one barrier/step (double-buffered hbuf)
    #pragma unroll 1
    for (int k = 0; k <= Tlen; ++k) {
        const int cur = k & 1, nxt = cur ^ 1;
        const _Float16* h0b = hbuf[cur][0];
        f16x8 a0 = read_h_frag(h0b, 0, l);
        f16x8 a1 = read_h_frag(h0b, 1, l);

        if (!isL1) {
            // C init = token-gate table quads (prefetched, already in regs)
            f32x4 acc0 = {tq0[0], tq1[0], tq2[0], tq3[0]};
            f32x4 acc1 = {tq0[1], tq1[1], tq2[1], tq3[1]};
            f32x4 acc2 = {tq0[2], tq1[2], tq2[2], tq3[2]};
            f32x4 acc3 = {tq0[3], tq1[3], tq2[3], tq3[3]};
            acc0 = __builtin_amdgcn_mfma_f32_16x16x32_f16(a0, wA0[0], acc0, 0, 0, 0);
            acc0 = __builtin_amdgcn_mfma_f32_16x16x32_f16(a1, wA1[0], acc0, 0, 0, 0);
            acc1 = __builtin_amdgcn_mfma_f32_16x16x32_f16(a0, wA0[1], acc1, 0, 0, 0);
            acc1 = __builtin_amdgcn_mfma_f32_16x16x32_f16(a1, wA1[1], acc1, 0, 0, 0);
            acc2 = __builtin_amdgcn_mfma_f32_16x16x32_f16(a0, wA0[2], acc2, 0, 0, 0);
            acc2 = __builtin_amdgcn_mfma_f32_16x16x32_f16(a1, wA1[2], acc2, 0, 0, 0);
            acc3 = __builtin_amdgcn_mfma_f32_16x16x32_f16(a0, wA0[3], acc3, 0, 0, 0);
            acc3 = __builtin_amdgcn_mfma_f32_16x16x32_f16(a1, wA1[3], acc3, 0, 0, 0);

            // prefetch: table quads for k+1 (tokens tn*), tokens for k+2 — off critical path
            f32x4 q0 = *(const f32x4*)&stbl4[tn0 * 64 + cq0];
            f32x4 q1 = *(const f32x4*)&stbl4[tn1 * 64 + cq0];
            f32x4 q2 = *(const f32x4*)&stbl4[tn2 * 64 + cq0];
            f32x4 q3 = *(const f32x4*)&stbl4[tn3 * 64 + cq0];
            const int kk2 = (k + 2 < Tlen) ? (k + 2) : (Tlen - 1);
            int nn0 = sxl[sxbase + kk2], nn1 = sxl[sxbase + Tlen + kk2];
            int nn2 = sxl[sxbase + 2 * Tlen + kk2], nn3 = sxl[sxbase + 3 * Tlen + kk2];

            if (k < Tlen) {
                _Float16* hw = hbuf[nxt][0];
                #pragma unroll
                for (int i = 0; i < 4; ++i) {
                    float hv;
                    upd_elem(acc0[i], acc1[i], acc2[i], acc3[i], cst[i], hv);
                    write_h(hw, (l >> 4) * 4 + i, cq0, hv);
                }
            }
            tq0 = q0; tq1 = q1; tq2 = q2; tq3 = q3;
            tn0 = nn0; tn1 = nn1; tn2 = nn2; tn3 = nn3;
        } else {
            const _Float16* h1b = hbuf[cur][1];
            f16x8 b0f = read_h_frag(h1b, 0, l);
            f16x8 b1f = read_h_frag(h1b, 1, l);
            // two independent 2-deep chains per q: I-GEMM (x-path) and H-GEMM (recurrent)
            f32x4 aI0 = (f32x4)(b1v[0]), aI1 = (f32x4)(b1v[1]), aI2 = (f32x4)(b1v[2]), aI3 = (f32x4)(b1v[3]);
            f32x4 aH0 = (f32x4)(0.0f), aH1 = (f32x4)(0.0f), aH2 = (f32x4)(0.0f), aH3 = (f32x4)(0.0f);
            aI0 = __builtin_amdgcn_mfma_f32_16x16x32_f16(a0,  wI0[0], aI0, 0, 0, 0);
            aH0 = __builtin_amdgcn_mfma_f32_16x16x32_f16(b0f, wH0[0], aH0, 0, 0, 0);
            aI0 = __builtin_amdgcn_mfma_f32_16x16x32_f16(a1,  wI1[0], aI0, 0, 0, 0);
            aH0 = __builtin_amdgcn_mfma_f32_16x16x32_f16(b1f, wH1[0], aH0, 0, 0, 0);
            aI1 = __builtin_amdgcn_mfma_f32_16x16x32_f16(a0,  wI0[1], aI1, 0, 0, 0);
            aH1 = __builtin_amdgcn_mfma_f32_16x16x32_f16(b0f, wH0[1], aH1, 0, 0, 0);
            aI1 = __builtin_amdgcn_mfma_f32_16x16x32_f16(a1,  wI1[1], aI1, 0, 0, 0);
            aH1 = __builtin_amdgcn_mfma_f32_16x16x32_f16(b1f, wH1[1], aH1, 0, 0, 0);
            aI2 = __builtin_amdgcn_mfma_f32_16x16x32_f16(a0,  wI0[2], aI2, 0, 0, 0);
            aH2 = __builtin_amdgcn_mfma_f32_16x16x32_f16(b0f, wH0[2], aH2, 0, 0, 0);
            aI2 = __builtin_amdgcn_mfma_f32_16x16x32_f16(a1,  wI1[2], aI2, 0, 0, 0);
            aH2 = __builtin_amdgcn_mfma_f32_16x16x32_f16(b1f, wH1[2], aH2, 0, 0, 0);
            aI3 = __builtin_amdgcn_mfma_f32_16x16x32_f16(a0,  wI0[3], aI3, 0, 0, 0);
            aH3 = __builtin_amdgcn_mfma_f32_16x16x32_f16(b0f, wH0[3], aH3, 0, 0, 0);
            aI3 = __builtin_amdgcn_mfma_f32_16x16x32_f16(a1,  wI1[3], aI3, 0, 0, 0);
            aH3 = __builtin_amdgcn_mfma_f32_16x16x32_f16(b1f, wH1[3], aH3, 0, 0, 0);
            f32x4 acc0 = aI0 + aH0, acc1 = aI1 + aH1, acc2 = aI2 + aH2, acc3 = aI3 + aH3;

            if (k >= 1) {
                _Float16* hw = hbuf[nxt][1];
                #pragma unroll
                for (int i = 0; i < 4; ++i) {
                    float hv;
                    upd_elem(acc0[i], acc1[i], acc2[i], acc3[i], cst[i], hv);
                    const int r = (l >> 4) * 4 + i;
                    if (k == Tlen) sh1f[r][cq0] = hv;       // final h1 in fp32
                    else           write_h(hw, r, cq0, hv);
                }
            }
        }
        __syncthreads();
    }

    // logits = h1(T-1) @ Wfc^T + bfc  (fp32)
    if (tid < SEQB * VOC) {
        const int seq = tid >> 3, v = tid & 7;
        float acc2 = bfc[v];
        #pragma unroll
        for (int j = 0; j < HDIM; ++j)
            acc2 += Wfc[v * HDIM + j] * sh1f[seq][j];
        out[(b0 + seq) * VOC + v] = acc2;
    }
}

extern "C" void kernel_launch(void* const* d_in, const int* in_sizes, int n_in,
                              void* d_out, int out_size, void* d_ws, size_t ws_size,
                              hipStream_t stream) {
    const int*   x    = (const int*)  d_in[0];
    const float* emb  = (const float*)d_in[1];
    const float* Wih0 = (const float*)d_in[2];
    const float* Whh0 = (const float*)d_in[3];
    const float* bih0 = (const float*)d_in[4];
    const float* bhh0 = (const float*)d_in[5];
    const float* Wih1 = (const float*)d_in[6];
    const float* Whh1 = (const float*)d_in[7];
    const float* bih1 = (const float*)d_in[8];
    const float* bhh1 = (const float*)d_in[9];
    const float* Wfc  = (const float*)d_in[10];
    const float* bfc  = (const float*)d_in[11];
    float* out = (float*)d_out;
    float* ws  = (float*)d_ws;

    hipLaunchKernelGGL(precompute_kernel, dim3(VOC + 1), dim3(G4), 0, stream,
                       emb, Wih0, bih0, bhh0, bih1, bhh1, ws);
    hipLaunchKernelGGL(lstm_kernel, dim3(NBLK), dim3(NT), 0, stream,
                       x, Whh0, Wih1, Whh1, Wfc, bfc, ws, out);
}

// Round 6
// 377.543 us; speedup vs baseline: 1.3670x; 1.3670x over previous
//
#include <hip/hip_runtime.h>

#define Bsz   1024
#define Tlen  512
#define VOC   8
#define EDIM  32
#define HDIM  64
#define G4    256
#define SEQB  4                  // sequences per block (rows 0-3 of the M=16 tile)
#define NT    512                // 8 waves
#define NBLK  (Bsz / SEQB)       // 256 blocks -> all 256 CUs

typedef _Float16 f16x8 __attribute__((ext_vector_type(8)));
typedef float    f32x4 __attribute__((ext_vector_type(4)));

__device__ __forceinline__ float ex2(float x) {
#if __has_builtin(__builtin_amdgcn_exp2f)
    return __builtin_amdgcn_exp2f(x);
#else
    return exp2f(x);
#endif
}
__device__ __forceinline__ float rcp_(float x) {
#if __has_builtin(__builtin_amdgcn_rcpf)
    return __builtin_amdgcn_rcpf(x);
#else
    return 1.0f / x;
#endif
}

// paired-rcp LSTM cell update: 5 exp2 + 3 rcp (+clamps) per (seq,col)
__device__ __forceinline__ void cell_upd(float ai, float af, float ag, float ao,
                                         float& c, float& h) {
    const float K1 = 1.4426950408889634f;
    float ei = ex2(fminf(-K1 * ai, 60.0f));
    float ef = ex2(fminf(-K1 * af, 60.0f));
    float eg = ex2(fminf(-2.0f * K1 * ag, 60.0f));
    float eo = ex2(fminf(-K1 * ao, 60.0f));
    float di = 1.0f + ei, df = 1.0f + ef, dg = 1.0f + eg, dn = 1.0f + eo;
    float r1 = rcp_(di * df);
    float si = df * r1;                                  // sigmoid(ai)
    float sf = di * r1;                                  // sigmoid(af)
    float r2 = rcp_(dg * dn);
    float tg = __builtin_fmaf(2.0f * dn, r2, -1.0f);     // tanh(ag)
    float so = dg * r2;                                  // sigmoid(ao)
    c = sf * c + si * tg;
    float ec = ex2(fminf(-2.0f * K1 * c, 60.0f));
    h = so * __builtin_fmaf(2.0f, rcp_(1.0f + ec), -1.0f);
}

// ws: [0 .. 2048) packed layer0 gate table: float4{i,f,g,o}[voc][hcol]
//     [2048 .. 2304) bih1+bhh1 (row-major gate index 64q+c)
__global__ void precompute_kernel(const float* __restrict__ emb,
                                  const float* __restrict__ Wih0,
                                  const float* __restrict__ bih0,
                                  const float* __restrict__ bhh0,
                                  const float* __restrict__ bih1,
                                  const float* __restrict__ bhh1,
                                  float* __restrict__ ws) {
    int g = threadIdx.x;
    int v = blockIdx.x;
    if (v < VOC) {
        float acc = bih0[g] + bhh0[g];
        #pragma unroll
        for (int e = 0; e < EDIM; ++e)
            acc += Wih0[g * EDIM + e] * emb[v * EDIM + e];
        const int q = g >> 6, c = g & 63;
        ws[(v * 64 + c) * 4 + q] = acc;
    } else {
        ws[VOC * G4 + g] = bih1[g] + bhh1[g];
    }
}

// h LDS layout = A-fragment order for mfma_f32_16x16x32_f16 (validated R4):
__device__ __forceinline__ f16x8 read_h_frag(const _Float16* hb, int kc, int l) {
    int off = kc * 512 + ((l * 8) ^ ((l & 3) << 7));
    return *(const f16x8*)(hb + off);
}
__device__ __forceinline__ void write_h(_Float16* hb, int r, int c, float v) {
    int off = (c >> 5) * 512 +
              (((((c & 31) >> 3) * 128) + r * 8 + (c & 7)) ^ ((r & 3) << 7));
    hb[off] = (_Float16)v;
}

// pull reg (l>>4) of a D-tile quad from lane (l&15): one gate value per lane
__device__ __forceinline__ float redist(f32x4 acc, int src, int s) {
    float v0 = __shfl(acc[0], src);
    float v1 = __shfl(acc[1], src);
    float v2 = __shfl(acc[2], src);
    float v3 = __shfl(acc[3], src);
    float r01 = (s & 1) ? v1 : v0;
    float r23 = (s & 1) ? v3 : v2;
    return (s & 2) ? r23 : r01;
}

__global__ __launch_bounds__(NT)
void lstm_kernel(const int*   __restrict__ x,
                 const float* __restrict__ Whh0,
                 const float* __restrict__ Wih1,
                 const float* __restrict__ Whh1,
                 const float* __restrict__ Wfc,
                 const float* __restrict__ bfc,
                 const float* __restrict__ ws,
                 float* __restrict__ out) {
    __shared__ float4    stbl4[VOC * 64];        // 8 KB packed gate table
    __shared__ int       sxl[SEQB * Tlen];       // 8 KB tokens [seq][t]
    __shared__ _Float16  hbuf[2][2][1024];       // 8 KB [buf][layer]; rows 4-15 stay 0
    __shared__ float     sh1f[SEQB][HDIM + 1];   // final h1, fp32

    const int tid  = threadIdx.x;
    const int b0   = blockIdx.x * SEQB;
    const int l    = tid & 63;
    const int wid  = tid >> 6;
    const bool isL1 = (wid >= 4);
    const int w    = wid & 3;                    // col block: cols [16w,16w+16)
    const int l15  = l & 15;
    const int kb   = (l >> 4) * 8;
    const int cq0  = 16 * w + l15;               // this lane's hidden col
    const int s    = l >> 4;                     // this lane's assigned seq (0..3)
    const int src  = l & 15;                     // redistribution source lane

    for (int i = tid; i < VOC * 64; i += NT)
        stbl4[i] = ((const float4*)ws)[i];
    for (int i = tid; i < SEQB * Tlen; i += NT)
        sxl[i] = x[b0 * Tlen + i];
    for (int i = tid; i < 2 * 2 * 1024; i += NT)
        ((_Float16*)hbuf)[i] = (_Float16)0.0f;

    // loop-invariant weight B-fragments: lane holds W[col=64q+16w+l15][kc*32+kb+i]
    f16x8 wA0[4], wA1[4], wI0[4], wI1[4], wH0[4], wH1[4];
    float b1v[4];
    if (!isL1) {
        #pragma unroll
        for (int q = 0; q < 4; ++q) {
            const int cq = 64 * q + cq0;
            const float* p0 = Whh0 + cq * HDIM + kb;
            const float* p1 = Whh0 + cq * HDIM + 32 + kb;
            #pragma unroll
            for (int i = 0; i < 8; ++i) { wA0[q][i] = (_Float16)p0[i]; wA1[q][i] = (_Float16)p1[i]; }
        }
    } else {
        #pragma unroll
        for (int q = 0; q < 4; ++q) {
            const int cq = 64 * q + cq0;
            b1v[q] = ws[VOC * G4 + cq];
            const float* pi0 = Wih1 + cq * HDIM + kb;
            const float* pi1 = Wih1 + cq * HDIM + 32 + kb;
            const float* ph0 = Whh1 + cq * HDIM + kb;
            const float* ph1 = Whh1 + cq * HDIM + 32 + kb;
            #pragma unroll
            for (int i = 0; i < 8; ++i) {
                wI0[q][i] = (_Float16)pi0[i]; wI1[q][i] = (_Float16)pi1[i];
                wH0[q][i] = (_Float16)ph0[i]; wH1[q][i] = (_Float16)ph1[i];
            }
        }
    }

    float cst = 0.0f;            // cell state for (seq s, col cq0)
    __syncthreads();

    int tc = 0;
    if (!isL1) tc = sxl[s * Tlen];   // token for step 0 (per assigned seq)

    // iter k: layer0 step t=k, layer1 step t=k-1; one barrier/step
    #pragma unroll 1
    for (int k = 0; k <= Tlen; ++k) {
        const int cur = k & 1, nxt = cur ^ 1;
        const _Float16* h0b = hbuf[cur][0];
        f16x8 a0 = read_h_frag(h0b, 0, l);
        f16x8 a1 = read_h_frag(h0b, 1, l);

        if (!isL1) {
            f32x4 tq = *(const f32x4*)&stbl4[tc * 64 + cq0];   // issue gather early
            f32x4 acc0 = (f32x4)(0.0f), acc1 = (f32x4)(0.0f);
            f32x4 acc2 = (f32x4)(0.0f), acc3 = (f32x4)(0.0f);
            acc0 = __builtin_amdgcn_mfma_f32_16x16x32_f16(a0, wA0[0], acc0, 0, 0, 0);
            acc1 = __builtin_amdgcn_mfma_f32_16x16x32_f16(a0, wA0[1], acc1, 0, 0, 0);
            acc2 = __builtin_amdgcn_mfma_f32_16x16x32_f16(a0, wA0[2], acc2, 0, 0, 0);
            acc3 = __builtin_amdgcn_mfma_f32_16x16x32_f16(a0, wA0[3], acc3, 0, 0, 0);
            acc0 = __builtin_amdgcn_mfma_f32_16x16x32_f16(a1, wA1[0], acc0, 0, 0, 0);
            acc1 = __builtin_amdgcn_mfma_f32_16x16x32_f16(a1, wA1[1], acc1, 0, 0, 0);
            acc2 = __builtin_amdgcn_mfma_f32_16x16x32_f16(a1, wA1[2], acc2, 0, 0, 0);
            acc3 = __builtin_amdgcn_mfma_f32_16x16x32_f16(a1, wA1[3], acc3, 0, 0, 0);

            const int kn = (k + 1 < Tlen) ? (k + 1) : (Tlen - 1);
            const int tnext = sxl[s * Tlen + kn];               // prefetch next token

            if (k < Tlen) {
                float ai = redist(acc0, src, s) + tq[0];
                float af = redist(acc1, src, s) + tq[1];
                float ag = redist(acc2, src, s) + tq[2];
                float ao = redist(acc3, src, s) + tq[3];
                float hv;
                cell_upd(ai, af, ag, ao, cst, hv);
                write_h(hbuf[nxt][0], s, cq0, hv);
            }
            tc = tnext;
        } else {
            const _Float16* h1b = hbuf[cur][1];
            f16x8 b0f = read_h_frag(h1b, 0, l);
            f16x8 b1f = read_h_frag(h1b, 1, l);
            f32x4 acc0 = (f32x4)(b1v[0]), acc1 = (f32x4)(b1v[1]);
            f32x4 acc2 = (f32x4)(b1v[2]), acc3 = (f32x4)(b1v[3]);
            acc0 = __builtin_amdgcn_mfma_f32_16x16x32_f16(a0,  wI0[0], acc0, 0, 0, 0);
            acc1 = __builtin_amdgcn_mfma_f32_16x16x32_f16(a0,  wI0[1], acc1, 0, 0, 0);
            acc2 = __builtin_amdgcn_mfma_f32_16x16x32_f16(a0,  wI0[2], acc2, 0, 0, 0);
            acc3 = __builtin_amdgcn_mfma_f32_16x16x32_f16(a0,  wI0[3], acc3, 0, 0, 0);
            acc0 = __builtin_amdgcn_mfma_f32_16x16x32_f16(a1,  wI1[0], acc0, 0, 0, 0);
            acc1 = __builtin_amdgcn_mfma_f32_16x16x32_f16(a1,  wI1[1], acc1, 0, 0, 0);
            acc2 = __builtin_amdgcn_mfma_f32_16x16x32_f16(a1,  wI1[2], acc2, 0, 0, 0);
            acc3 = __builtin_amdgcn_mfma_f32_16x16x32_f16(a1,  wI1[3], acc3, 0, 0, 0);
            acc0 = __builtin_amdgcn_mfma_f32_16x16x32_f16(b0f, wH0[0], acc0, 0, 0, 0);
            acc1 = __builtin_amdgcn_mfma_f32_16x16x32_f16(b0f, wH0[1], acc1, 0, 0, 0);
            acc2 = __builtin_amdgcn_mfma_f32_16x16x32_f16(b0f, wH0[2], acc2, 0, 0, 0);
            acc3 = __builtin_amdgcn_mfma_f32_16x16x32_f16(b0f, wH0[3], acc3, 0, 0, 0);
            acc0 = __builtin_amdgcn_mfma_f32_16x16x32_f16(b1f, wH1[0], acc0, 0, 0, 0);
            acc1 = __builtin_amdgcn_mfma_f32_16x16x32_f16(b1f, wH1[1], acc1, 0, 0, 0);
            acc2 = __builtin_amdgcn_mfma_f32_16x16x32_f16(b1f, wH1[2], acc2, 0, 0, 0);
            acc3 = __builtin_amdgcn_mfma_f32_16x16x32_f16(b1f, wH1[3], acc3, 0, 0, 0);

            if (k >= 1) {
                float ai = redist(acc0, src, s);
                float af = redist(acc1, src, s);
                float ag = redist(acc2, src, s);
                float ao = redist(acc3, src, s);
                float hv;
                cell_upd(ai, af, ag, ao, cst, hv);
                if (k == Tlen) sh1f[s][cq0] = hv;       // final h1 in fp32
                else           write_h(hbuf[nxt][1], s, cq0, hv);
            }
        }
        __syncthreads();
    }

    // logits = h1(T-1) @ Wfc^T + bfc  (fp32)
    if (tid < SEQB * VOC) {
        const int seq = tid >> 3, v = tid & 7;
        float acc2 = bfc[v];
        #pragma unroll
        for (int j = 0; j < HDIM; ++j)
            acc2 += Wfc[v * HDIM + j] * sh1f[seq][j];
        out[(b0 + seq) * VOC + v] = acc2;
    }
}

extern "C" void kernel_launch(void* const* d_in, const int* in_sizes, int n_in,
                              void* d_out, int out_size, void* d_ws, size_t ws_size,
                              hipStream_t stream) {
    const int*   x    = (const int*)  d_in[0];
    const float* emb  = (const float*)d_in[1];
    const float* Wih0 = (const float*)d_in[2];
    const float* Whh0 = (const float*)d_in[3];
    const float* bih0 = (const float*)d_in[4];
    const float* bhh0 = (const float*)d_in[5];
    const float* Wih1 = (const float*)d_in[6];
    const float* Whh1 = (const float*)d_in[7];
    const float* bih1 = (const float*)d_in[8];
    const float* bhh1 = (const float*)d_in[9];
    const float* Wfc  = (const float*)d_in[10];
    const float* bfc  = (const float*)d_in[11];
    float* out = (float*)d_out;
    float* ws  = (float*)d_ws;

    hipLaunchKernelGGL(precompute_kernel, dim3(VOC + 1), dim3(G4), 0, stream,
                       emb, Wih0, bih0, bhh0, bih1, bhh1, ws);
    hipLaunchKernelGGL(lstm_kernel, dim3(NBLK), dim3(NT), 0, stream,
                       x, Whh0, Wih1, Whh1, Wfc, bfc, ws, out);
}

// Round 7
// 222.685 us; speedup vs baseline: 2.3177x; 1.6954x over previous
//
#include <hip/hip_runtime.h>

#define Bsz   1024
#define Tlen  512
#define VOC   8
#define EDIM  32
#define HDIM  64
#define G4    256
#define SEQB  4                  // sequences per block, mapped to A-rows {0,4,8,12}
#define NT    512                // 8 waves
#define NBLK  (Bsz / SEQB)       // 256 blocks -> all 256 CUs

typedef _Float16 f16x8 __attribute__((ext_vector_type(8)));
typedef float    f32x4 __attribute__((ext_vector_type(4)));

__device__ __forceinline__ float ex2(float x) {
#if __has_builtin(__builtin_amdgcn_exp2f)
    return __builtin_amdgcn_exp2f(x);
#else
    return exp2f(x);
#endif
}
__device__ __forceinline__ float rcp_(float x) {
#if __has_builtin(__builtin_amdgcn_rcpf)
    return __builtin_amdgcn_rcpf(x);
#else
    return 1.0f / x;
#endif
}

// paired-rcp LSTM cell update: 5 exp2 + 3 rcp (+clamps) per (seq,col)
__device__ __forceinline__ void cell_upd(float ai, float af, float ag, float ao,
                                         float& c, float& h) {
    const float K1 = 1.4426950408889634f;
    float ei = ex2(fminf(-K1 * ai, 60.0f));
    float ef = ex2(fminf(-K1 * af, 60.0f));
    float eg = ex2(fminf(-2.0f * K1 * ag, 60.0f));
    float eo = ex2(fminf(-K1 * ao, 60.0f));
    float di = 1.0f + ei, df = 1.0f + ef, dg = 1.0f + eg, dn = 1.0f + eo;
    float r1 = rcp_(di * df);
    float si = df * r1;                                  // sigmoid(ai)
    float sf = di * r1;                                  // sigmoid(af)
    float r2 = rcp_(dg * dn);
    float tg = __builtin_fmaf(2.0f * dn, r2, -1.0f);     // tanh(ag)
    float so = dg * r2;                                  // sigmoid(ao)
    c = sf * c + si * tg;
    float ec = ex2(fminf(-2.0f * K1 * c, 60.0f));
    h = so * __builtin_fmaf(2.0f, rcp_(1.0f + ec), -1.0f);
}

// ws: [0 .. 2048) packed layer0 gate table: float4{i,f,g,o}[voc][hcol]
//     [2048 .. 2304) bih1+bhh1 (gate index 64q+c)
__global__ void precompute_kernel(const float* __restrict__ emb,
                                  const float* __restrict__ Wih0,
                                  const float* __restrict__ bih0,
                                  const float* __restrict__ bhh0,
                                  const float* __restrict__ bih1,
                                  const float* __restrict__ bhh1,
                                  float* __restrict__ ws) {
    int g = threadIdx.x;
    int v = blockIdx.x;
    if (v < VOC) {
        float acc = bih0[g] + bhh0[g];
        #pragma unroll
        for (int e = 0; e < EDIM; ++e)
            acc += Wih0[g * EDIM + e] * emb[v * EDIM + e];
        const int q = g >> 6, c = g & 63;
        ws[(v * 64 + c) * 4 + q] = acc;
    } else {
        ws[VOC * G4 + g] = bih1[g] + bhh1[g];
    }
}

// h LDS layout = A-fragment order for mfma_f32_16x16x32_f16 (validated R4):
__device__ __forceinline__ f16x8 read_h_frag(const _Float16* hb, int kc, int l) {
    int off = kc * 512 + ((l * 8) ^ ((l & 3) << 7));
    return *(const f16x8*)(hb + off);
}
__device__ __forceinline__ void write_h(_Float16* hb, int r, int c, float v) {
    int off = (c >> 5) * 512 +
              (((((c & 31) >> 3) * 128) + r * 8 + (c & 7)) ^ ((r & 3) << 7));
    hb[off] = (_Float16)v;
}

__global__ __launch_bounds__(NT)
void lstm_kernel(const int*   __restrict__ x,
                 const float* __restrict__ Whh0,
                 const float* __restrict__ Wih1,
                 const float* __restrict__ Whh1,
                 const float* __restrict__ Wfc,
                 const float* __restrict__ bfc,
                 const float* __restrict__ ws,
                 float* __restrict__ out) {
    __shared__ float4    stbl4[VOC * 64];        // 8 KB packed gate table
    __shared__ int       sxl[SEQB * Tlen];       // 8 KB tokens [seq][t]
    __shared__ _Float16  hbuf[2][2][1024];       // 8 KB [buf][layer]; only rows {0,4,8,12} written
    __shared__ float     sh1f[SEQB][HDIM + 1];   // final h1, fp32

    const int tid  = threadIdx.x;
    const int b0   = blockIdx.x * SEQB;
    const int l    = tid & 63;
    const int wid  = tid >> 6;
    const bool isL1 = (wid >= 4);
    const int w    = wid & 3;                    // col block: cols [16w,16w+16)
    const int l15  = l & 15;
    const int kb   = (l >> 4) * 8;
    const int cq0  = 16 * w + l15;               // this lane's hidden col
    const int s    = l >> 4;                     // this lane's assigned seq (0..3) -> A-row 4s
    const int r4   = 4 * s;                      // seq's A/D row

    for (int i = tid; i < VOC * 64; i += NT)
        stbl4[i] = ((const float4*)ws)[i];
    for (int i = tid; i < SEQB * Tlen; i += NT)
        sxl[i] = x[b0 * Tlen + i];
    for (int i = tid; i < 2 * 2 * 1024; i += NT)
        ((_Float16*)hbuf)[i] = (_Float16)0.0f;

    // loop-invariant weight B-fragments: lane holds W[col=64q+16w+l15][kc*32+kb+i]
    f16x8 wA0[4], wA1[4], wI0[4], wI1[4], wH0[4], wH1[4];
    float b1s[4];
    if (!isL1) {
        #pragma unroll
        for (int q = 0; q < 4; ++q) {
            const int cq = 64 * q + cq0;
            const float* p0 = Whh0 + cq * HDIM + kb;
            const float* p1 = Whh0 + cq * HDIM + 32 + kb;
            #pragma unroll
            for (int i = 0; i < 8; ++i) { wA0[q][i] = (_Float16)p0[i]; wA1[q][i] = (_Float16)p1[i]; }
        }
    } else {
        #pragma unroll
        for (int q = 0; q < 4; ++q) {
            const int cq = 64 * q + cq0;
            b1s[q] = ws[VOC * G4 + cq];          // bias for (gate q, col cq0), added post-MFMA
            const float* pi0 = Wih1 + cq * HDIM + kb;
            const float* pi1 = Wih1 + cq * HDIM + 32 + kb;
            const float* ph0 = Whh1 + cq * HDIM + kb;
            const float* ph1 = Whh1 + cq * HDIM + 32 + kb;
            #pragma unroll
            for (int i = 0; i < 8; ++i) {
                wI0[q][i] = (_Float16)pi0[i]; wI1[q][i] = (_Float16)pi1[i];
                wH0[q][i] = (_Float16)ph0[i]; wH1[q][i] = (_Float16)ph1[i];
            }
        }
    }

    float cst = 0.0f;            // cell state for (seq s, col cq0)
    __syncthreads();

    int tc = 0;
    if (!isL1) tc = sxl[s * Tlen];   // token for step 0 (per assigned seq)

    // iter k: layer0 step t=k, layer1 step t=k-1; one barrier/step
    #pragma unroll 1
    for (int k = 0; k <= Tlen; ++k) {
        const int cur = k & 1, nxt = cur ^ 1;
        const _Float16* h0b = hbuf[cur][0];
        f16x8 a0 = read_h_frag(h0b, 0, l);
        f16x8 a1 = read_h_frag(h0b, 1, l);

        if (!isL1) {
            f32x4 tq = *(const f32x4*)&stbl4[tc * 64 + cq0];   // issue gather early
            f32x4 acc0 = (f32x4)(0.0f), acc1 = (f32x4)(0.0f);
            f32x4 acc2 = (f32x4)(0.0f), acc3 = (f32x4)(0.0f);
            acc0 = __builtin_amdgcn_mfma_f32_16x16x32_f16(a0, wA0[0], acc0, 0, 0, 0);
            acc1 = __builtin_amdgcn_mfma_f32_16x16x32_f16(a0, wA0[1], acc1, 0, 0, 0);
            acc2 = __builtin_amdgcn_mfma_f32_16x16x32_f16(a0, wA0[2], acc2, 0, 0, 0);
            acc3 = __builtin_amdgcn_mfma_f32_16x16x32_f16(a0, wA0[3], acc3, 0, 0, 0);
            acc0 = __builtin_amdgcn_mfma_f32_16x16x32_f16(a1, wA1[0], acc0, 0, 0, 0);
            acc1 = __builtin_amdgcn_mfma_f32_16x16x32_f16(a1, wA1[1], acc1, 0, 0, 0);
            acc2 = __builtin_amdgcn_mfma_f32_16x16x32_f16(a1, wA1[2], acc2, 0, 0, 0);
            acc3 = __builtin_amdgcn_mfma_f32_16x16x32_f16(a1, wA1[3], acc3, 0, 0, 0);

            const int kn = (k + 1 < Tlen) ? (k + 1) : (Tlen - 1);
            const int tnext = sxl[s * Tlen + kn];               // prefetch next token

            if (k < Tlen) {
                // D reg 0 = row 4s = this lane's (seq, col): no redistribution needed
                float ai = acc0[0] + tq[0];
                float af = acc1[0] + tq[1];
                float ag = acc2[0] + tq[2];
                float ao = acc3[0] + tq[3];
                float hv;
                cell_upd(ai, af, ag, ao, cst, hv);
                write_h(hbuf[nxt][0], r4, cq0, hv);
            }
            tc = tnext;
        } else {
            const _Float16* h1b = hbuf[cur][1];
            f16x8 b0f = read_h_frag(h1b, 0, l);
            f16x8 b1f = read_h_frag(h1b, 1, l);
            f32x4 acc0 = (f32x4)(0.0f), acc1 = (f32x4)(0.0f);
            f32x4 acc2 = (f32x4)(0.0f), acc3 = (f32x4)(0.0f);
            acc0 = __builtin_amdgcn_mfma_f32_16x16x32_f16(a0,  wI0[0], acc0, 0, 0, 0);
            acc1 = __builtin_amdgcn_mfma_f32_16x16x32_f16(a0,  wI0[1], acc1, 0, 0, 0);
            acc2 = __builtin_amdgcn_mfma_f32_16x16x32_f16(a0,  wI0[2], acc2, 0, 0, 0);
            acc3 = __builtin_amdgcn_mfma_f32_16x16x32_f16(a0,  wI0[3], acc3, 0, 0, 0);
            acc0 = __builtin_amdgcn_mfma_f32_16x16x32_f16(a1,  wI1[0], acc0, 0, 0, 0);
            acc1 = __builtin_amdgcn_mfma_f32_16x16x32_f16(a1,  wI1[1], acc1, 0, 0, 0);
            acc2 = __builtin_amdgcn_mfma_f32_16x16x32_f16(a1,  wI1[2], acc2, 0, 0, 0);
            acc3 = __builtin_amdgcn_mfma_f32_16x16x32_f16(a1,  wI1[3], acc3, 0, 0, 0);
            acc0 = __builtin_amdgcn_mfma_f32_16x16x32_f16(b0f, wH0[0], acc0, 0, 0, 0);
            acc1 = __builtin_amdgcn_mfma_f32_16x16x32_f16(b0f, wH0[1], acc1, 0, 0, 0);
            acc2 = __builtin_amdgcn_mfma_f32_16x16x32_f16(b0f, wH0[2], acc2, 0, 0, 0);
            acc3 = __builtin_amdgcn_mfma_f32_16x16x32_f16(b0f, wH0[3], acc3, 0, 0, 0);
            acc0 = __builtin_amdgcn_mfma_f32_16x16x32_f16(b1f, wH1[0], acc0, 0, 0, 0);
            acc1 = __builtin_amdgcn_mfma_f32_16x16x32_f16(b1f, wH1[1], acc1, 0, 0, 0);
            acc2 = __builtin_amdgcn_mfma_f32_16x16x32_f16(b1f, wH1[2], acc2, 0, 0, 0);
            acc3 = __builtin_amdgcn_mfma_f32_16x16x32_f16(b1f, wH1[3], acc3, 0, 0, 0);

            if (k >= 1) {
                float ai = acc0[0] + b1s[0];
                float af = acc1[0] + b1s[1];
                float ag = acc2[0] + b1s[2];
                float ao = acc3[0] + b1s[3];
                float hv;
                cell_upd(ai, af, ag, ao, cst, hv);
                if (k == Tlen) sh1f[s][cq0] = hv;       // final h1 in fp32
                else           write_h(hbuf[nxt][1], r4, cq0, hv);
            }
        }
        __syncthreads();
    }

    // logits = h1(T-1) @ Wfc^T + bfc  (fp32)
    if (tid < SEQB * VOC) {
        const int seq = tid >> 3, v = tid & 7;
        float acc2 = bfc[v];
        #pragma unroll
        for (int j = 0; j < HDIM; ++j)
            acc2 += Wfc[v * HDIM + j] * sh1f[seq][j];
        out[(b0 + seq) * VOC + v] = acc2;
    }
}

extern "C" void kernel_launch(void* const* d_in, const int* in_sizes, int n_in,
                              void* d_out, int out_size, void* d_ws, size_t ws_size,
                              hipStream_t stream) {
    const int*   x    = (const int*)  d_in[0];
    const float* emb  = (const float*)d_in[1];
    const float* Wih0 = (const float*)d_in[2];
    const float* Whh0 = (const float*)d_in[3];
    const float* bih0 = (const float*)d_in[4];
    const float* bhh0 = (const float*)d_in[5];
    const float* Wih1 = (const float*)d_in[6];
    const float* Whh1 = (const float*)d_in[7];
    const float* bih1 = (const float*)d_in[8];
    const float* bhh1 = (const float*)d_in[9];
    const float* Wfc  = (const float*)d_in[10];
    const float* bfc  = (const float*)d_in[11];
    float* out = (float*)d_out;
    float* ws  = (float*)d_ws;

    hipLaunchKernelGGL(precompute_kernel, dim3(VOC + 1), dim3(G4), 0, stream,
                       emb, Wih0, bih0, bhh0, bih1, bhh1, ws);
    hipLaunchKernelGGL(lstm_kernel, dim3(NBLK), dim3(NT), 0, stream,
                       x, Whh0, Wih1, Whh1, Wfc, bfc, ws, out);
}